// Round 3
// baseline (49.670 us; speedup 1.0000x reference)
//
#include <hip/hip_runtime.h>

// FACoef: out[b] = sum_{i,j} coef[i,j] * S_{i+2}(b)^{j+1} / n^{i+j+2}
// where S_k(b) = sum of all entries of x_b^k (k=2,3,4), n = G*G.
// Identities: u1 = 1^T x (col sums), v1 = x 1 (row sums),
//   u2 = u1 x, v2 = x v1;  S2 = u1.v1, S3 = u2.v1, S4 = u2.v2.
// One read of x (268 MB total), one matvec round. Memory-bound.
// 1024 thr/block, 4 rows x 4 cols per thread -> ~50 live VGPRs, cap 64
// via __launch_bounds__(1024,8) => 2 blocks/CU (8 waves/SIMD).

#define G 128

typedef float v4f __attribute__((ext_vector_type(4)));

__global__ __launch_bounds__(1024, 8) void facoef_kernel(
    const float* __restrict__ x, const float* __restrict__ coef,
    float* __restrict__ out) {
  const int b = blockIdx.x;
  const int tid = threadIdx.x;
  const int cg = tid & 31;   // cols [4*cg, 4*cg+3]
  const int rh = tid >> 5;   // rows [4*rh, 4*rh+3]  (rh = 0..31)
  const int lane = tid & 63;

  __shared__ float part[32][128];   // per-rowgroup column partials
  __shared__ float part2[4][128];   // stage-2 column partials
  __shared__ float u1s[128], v1s[128], v2s[128];
  __shared__ float Sp[3][2];

  const float* xb = x + (size_t)b * (G * G);

  // Load 4x4 slice of x into regs (coalesced dwordx4, read x exactly once).
  v4f xs[4];
#pragma unroll
  for (int r = 0; r < 4; ++r)
    xs[r] = *(const v4f*)(xb + (rh * 4 + r) * G + cg * 4);

  // ---- u1 column partials + v1 row sums (shfl within 32-lane halves) ----
  v4f acc = xs[0] + xs[1] + xs[2] + xs[3];
  *(v4f*)&part[rh][cg * 4] = acc;

  float rs[4];
#pragma unroll
  for (int r = 0; r < 4; ++r) rs[r] = xs[r].x + xs[r].y + xs[r].z + xs[r].w;
#pragma unroll
  for (int off = 1; off < 32; off <<= 1) {
#pragma unroll
    for (int r = 0; r < 4; ++r) rs[r] += __shfl_xor(rs[r], off, 64);
  }
  if (cg == 0) {
#pragma unroll
    for (int r = 0; r < 4; ++r) v1s[rh * 4 + r] = rs[r];
  }
  __syncthreads();

  if (tid < 512) {
    const int c = tid & 127, q = tid >> 7;
    float s = 0.f;
#pragma unroll
    for (int h = 0; h < 8; ++h) s += part[q * 8 + h][c];
    part2[q][c] = s;
  }
  __syncthreads();
  if (tid < 128)
    u1s[tid] = part2[0][tid] + part2[1][tid] + part2[2][tid] + part2[3][tid];
  __syncthreads();

  // ---- one matvec round: u2 = u1 x (col partials), v2 = x v1 (row dots) ----
  v4f a = {0.f, 0.f, 0.f, 0.f};
  const v4f v1f = *(const v4f*)&v1s[cg * 4];
  float pd[4];
#pragma unroll
  for (int r = 0; r < 4; ++r) {
    a += u1s[rh * 4 + r] * xs[r];
    v4f p = xs[r] * v1f;
    pd[r] = p.x + p.y + p.z + p.w;
  }
  *(v4f*)&part[rh][cg * 4] = a;
#pragma unroll
  for (int off = 1; off < 32; off <<= 1) {
#pragma unroll
    for (int r = 0; r < 4; ++r) pd[r] += __shfl_xor(pd[r], off, 64);
  }
  if (cg == 0) {
#pragma unroll
    for (int r = 0; r < 4; ++r) v2s[rh * 4 + r] = pd[r];
  }
  __syncthreads();

  if (tid < 512) {
    const int c = tid & 127, q = tid >> 7;
    float s = 0.f;
#pragma unroll
    for (int h = 0; h < 8; ++h) s += part[q * 8 + h][c];
    part2[q][c] = s;
  }
  __syncthreads();

  // ---- final: u2 column reduce + three 128-dots ----
  if (tid < 128) {
    const float u2 =
        part2[0][tid] + part2[1][tid] + part2[2][tid] + part2[3][tid];
    const float u1v = u1s[tid], v1v = v1s[tid], v2v = v2s[tid];
    float d2 = u1v * v1v;
    float d3 = u2 * v1v;
    float d4 = u2 * v2v;
#pragma unroll
    for (int off = 32; off > 0; off >>= 1) {
      d2 += __shfl_xor(d2, off, 64);
      d3 += __shfl_xor(d3, off, 64);
      d4 += __shfl_xor(d4, off, 64);
    }
    if (lane == 0) {
      Sp[0][tid >> 6] = d2;
      Sp[1][tid >> 6] = d3;
      Sp[2][tid >> 6] = d4;
    }
  }
  __syncthreads();

  if (tid == 0) {
    double S[3];
#pragma unroll
    for (int k = 0; k < 3; ++k) S[k] = (double)Sp[k][0] + (double)Sp[k][1];
    const double n = (double)(G * G);
    double np[7];
    np[2] = n * n;
    np[3] = np[2] * n;
    np[4] = np[3] * n;
    np[5] = np[4] * n;
    np[6] = np[5] * n;
    double o = 0.0;
#pragma unroll
    for (int i = 0; i < 3; ++i) {
      double s1 = S[i], s2 = s1 * s1, s3 = s2 * s1;
      double sp[3] = {s1, s2, s3};
#pragma unroll
      for (int j = 0; j < 3; ++j) {
        o += (double)coef[i * 3 + j] * sp[j] / np[i + j + 2];
      }
    }
    out[b] = (float)o;
  }
}

extern "C" void kernel_launch(void* const* d_in, const int* in_sizes, int n_in,
                              void* d_out, int out_size, void* d_ws, size_t ws_size,
                              hipStream_t stream) {
  const float* x = (const float*)d_in[0];
  const float* coef = (const float*)d_in[1];
  float* out = (float*)d_out;
  const int batch = in_sizes[0] / (G * G);
  facoef_kernel<<<batch, 1024, 0, stream>>>(x, coef, out);
}

// Round 4
// 48.359 us; speedup vs baseline: 1.0271x; 1.0271x over previous
//
#include <hip/hip_runtime.h>

// FACoef: out[b] = sum_{i,j} coef[i,j] * S_{i+2}(b)^{j+1} / n^{i+j+2}
// where S_k(b) = sum of all entries of x_b^k (k=2,3,4), n = G*G.
// Identities: u1 = 1^T x (col sums), v1 = x 1 (row sums),
//   u2 = u1 x, v2 = x v1;  S2 = u1.v1, S3 = u2.v1, S4 = u2.v2.
// One read of x (268 MB total), ONE matvec round, 4 barriers.
// 512 thr/block, 8 rows x 4 cols/thread (xs[8] = 32 VGPRs, peak ~60 live).
// __launch_bounds__(512,6): VGPR cap 80 (no spill) -> 3 blocks/CU so other
// blocks' loads cover this block's reduce/barrier tail.

#define G 128

typedef float v4f __attribute__((ext_vector_type(4)));

__global__ __launch_bounds__(512, 6) void facoef_kernel(
    const float* __restrict__ x, const float* __restrict__ coef,
    float* __restrict__ out) {
  const int b = blockIdx.x;
  const int tid = threadIdx.x;
  const int cg = tid & 31;   // cols [4*cg, 4*cg+3]
  const int rh = tid >> 5;   // rows [8*rh, 8*rh+7]
  const int lane = tid & 63;

  __shared__ float part[16][128];  // column-partials per row-chunk
  __shared__ float u1s[128], v1s[128], v2s[128];
  __shared__ float Sp[3][2];       // per-wave dot partials (2 waves of tid<128)

  const float* xb = x + (size_t)b * (G * G);

  // Load this thread's 8x4 slice of x (coalesced dwordx4), keep in regs.
  v4f xs[8];
#pragma unroll
  for (int r = 0; r < 8; ++r)
    xs[r] = *(const v4f*)(xb + (rh * 8 + r) * G + cg * 4);

  // ---- column-sum partials (u1) + row sums (v1, via shfl) ----
  v4f acc = xs[0];
#pragma unroll
  for (int r = 1; r < 8; ++r) acc += xs[r];
  *(v4f*)&part[rh][cg * 4] = acc;

  float rs[8];
#pragma unroll
  for (int r = 0; r < 8; ++r) rs[r] = xs[r].x + xs[r].y + xs[r].z + xs[r].w;
#pragma unroll
  for (int off = 1; off < 32; off <<= 1) {
#pragma unroll
    for (int r = 0; r < 8; ++r) rs[r] += __shfl_xor(rs[r], off, 64);
  }
  if (cg == 0) {
#pragma unroll
    for (int r = 0; r < 8; ++r) v1s[rh * 8 + r] = rs[r];
  }
  __syncthreads();  // part + v1s visible

  if (tid < 128) {
    float s = 0.f;
#pragma unroll
    for (int h = 0; h < 16; ++h) s += part[h][tid];
    u1s[tid] = s;
  }
  __syncthreads();  // u1s visible

  // ---- one matvec round: u2 = u1 x (col partials), v2 = x v1 (row dots) ----
  v4f a = {0.f, 0.f, 0.f, 0.f};
  const v4f v1f = *(const v4f*)&v1s[cg * 4];
  float pd[8];
#pragma unroll
  for (int r = 0; r < 8; ++r) {
    a += u1s[rh * 8 + r] * xs[r];
    v4f p = xs[r] * v1f;
    pd[r] = p.x + p.y + p.z + p.w;
  }
  *(v4f*)&part[rh][cg * 4] = a;
#pragma unroll
  for (int off = 1; off < 32; off <<= 1) {
#pragma unroll
    for (int r = 0; r < 8; ++r) pd[r] += __shfl_xor(pd[r], off, 64);
  }
  if (cg == 0) {
#pragma unroll
    for (int r = 0; r < 8; ++r) v2s[rh * 8 + r] = pd[r];
  }
  __syncthreads();  // part(u2) + v2s visible

  // ---- final: u2 column reduce + three 128-dots ----
  if (tid < 128) {
    float u2 = 0.f;
#pragma unroll
    for (int h = 0; h < 16; ++h) u2 += part[h][tid];
    const float u1v = u1s[tid], v1v = v1s[tid], v2v = v2s[tid];
    float d2 = u1v * v1v;
    float d3 = u2 * v1v;
    float d4 = u2 * v2v;
#pragma unroll
    for (int off = 32; off > 0; off >>= 1) {
      d2 += __shfl_xor(d2, off, 64);
      d3 += __shfl_xor(d3, off, 64);
      d4 += __shfl_xor(d4, off, 64);
    }
    if (lane == 0) {
      Sp[0][tid >> 6] = d2;
      Sp[1][tid >> 6] = d3;
      Sp[2][tid >> 6] = d4;
    }
  }
  __syncthreads();

  if (tid == 0) {
    double S[3];
#pragma unroll
    for (int k = 0; k < 3; ++k) S[k] = (double)Sp[k][0] + (double)Sp[k][1];
    const double n = (double)(G * G);
    double np[7];
    np[2] = n * n;
    np[3] = np[2] * n;
    np[4] = np[3] * n;
    np[5] = np[4] * n;
    np[6] = np[5] * n;
    double o = 0.0;
#pragma unroll
    for (int i = 0; i < 3; ++i) {
      double s1 = S[i], s2 = s1 * s1, s3 = s2 * s1;
      double sp[3] = {s1, s2, s3};
#pragma unroll
      for (int j = 0; j < 3; ++j) {
        o += (double)coef[i * 3 + j] * sp[j] / np[i + j + 2];
      }
    }
    out[b] = (float)o;
  }
}

extern "C" void kernel_launch(void* const* d_in, const int* in_sizes, int n_in,
                              void* d_out, int out_size, void* d_ws, size_t ws_size,
                              hipStream_t stream) {
  const float* x = (const float*)d_in[0];
  const float* coef = (const float*)d_in[1];
  float* out = (float*)d_out;
  const int batch = in_sizes[0] / (G * G);
  facoef_kernel<<<batch, 512, 0, stream>>>(x, coef, out);
}

// Round 5
// 45.893 us; speedup vs baseline: 1.0823x; 1.0537x over previous
//
#include <hip/hip_runtime.h>

// FACoef: out[b] = sum_{i,j} coef[i,j] * S_{i+2}(b)^{j+1} / n^{i+j+2}
// where S_k(b) = sum of all entries of x_b^k  (k = 2,3,4), n = G*G.
// Key identity: sum(x^k) = 1^T x^k 1, computed via a row-vector chain:
//   u1 = 1^T x (column sums), u_{k} = u_{k-1} x, S_k = sum(u_k).
// O(B*G^2) instead of O(B*G^3); memory-bound: read x exactly once.
// R4: identical structure to R0 (best: 45.8us); only change is
// __launch_bounds__(512,6) -> VGPR cap 80 (live ~55, no spill),
// 3 blocks/CU instead of 2 so another block's loads cover the
// reduce/barrier tail.

#define G 128

typedef float v4f __attribute__((ext_vector_type(4)));

__global__ __launch_bounds__(512, 6) void facoef_kernel(
    const float* __restrict__ x, const float* __restrict__ coef,
    float* __restrict__ out) {
  const int b = blockIdx.x;
  const int tid = threadIdx.x;
  const int cg = tid & 31;   // column group: cols [4*cg, 4*cg+3]
  const int rh = tid >> 5;   // row chunk:    rows [8*rh, 8*rh+7]

  __shared__ float part[16][128];  // per-rowchunk partials (lane-consecutive)
  __shared__ float u[128];         // current row-vector u_k
  __shared__ float Sp[3][2];       // S2,S3,S4 per-wave partials

  const float* xb = x + (size_t)b * (G * G);

  // Load this thread's 8x4 slice of x into registers (coalesced dwordx4).
  v4f xs[8];
#pragma unroll
  for (int r = 0; r < 8; ++r) {
    xs[r] = *(const v4f*)(xb + (rh * 8 + r) * G + cg * 4);
  }

  // ---- u1 = column sums ----
  v4f acc = xs[0];
#pragma unroll
  for (int r = 1; r < 8; ++r) acc += xs[r];
  *(v4f*)&part[rh][cg * 4] = acc;
  __syncthreads();

  if (tid < 128) {
    float s = 0.f;
#pragma unroll
    for (int h = 0; h < 16; ++h) s += part[h][tid];
    u[tid] = s;
  }
  __syncthreads();

  // ---- u2,u3 (stored) and S2,S3,S4 ----
  for (int k = 0; k < 3; ++k) {
    v4f a = {0.f, 0.f, 0.f, 0.f};
#pragma unroll
    for (int r = 0; r < 8; ++r) {
      float uv = u[rh * 8 + r];  // broadcast read
      a += uv * xs[r];
    }
    *(v4f*)&part[rh][cg * 4] = a;
    __syncthreads();

    if (tid < 128) {
      float s = 0.f;
#pragma unroll
      for (int h = 0; h < 16; ++h) s += part[h][tid];
      // wave-level sum over the 128 u-entries for S_{k+2}
      float t = s;
#pragma unroll
      for (int off = 32; off > 0; off >>= 1) t += __shfl_xor(t, off, 64);
      if ((tid & 63) == 0) Sp[k][tid >> 6] = t;
      if (k < 2) u[tid] = s;  // u_{k+2} feeds the next matvec
    }
    __syncthreads();
  }

  if (tid == 0) {
    double S[3];
#pragma unroll
    for (int k = 0; k < 3; ++k) S[k] = (double)Sp[k][0] + (double)Sp[k][1];
    const double n = (double)(G * G);
    double np[7];
    np[2] = n * n;
    np[3] = np[2] * n;
    np[4] = np[3] * n;
    np[5] = np[4] * n;
    np[6] = np[5] * n;
    double o = 0.0;
#pragma unroll
    for (int i = 0; i < 3; ++i) {
      double s1 = S[i], s2 = s1 * s1, s3 = s2 * s1;
      double sp[3] = {s1, s2, s3};
#pragma unroll
      for (int j = 0; j < 3; ++j) {
        o += (double)coef[i * 3 + j] * sp[j] / np[i + j + 2];
      }
    }
    out[b] = (float)o;
  }
}

extern "C" void kernel_launch(void* const* d_in, const int* in_sizes, int n_in,
                              void* d_out, int out_size, void* d_ws, size_t ws_size,
                              hipStream_t stream) {
  const float* x = (const float*)d_in[0];
  const float* coef = (const float*)d_in[1];
  float* out = (float*)d_out;
  const int batch = in_sizes[0] / (G * G);
  facoef_kernel<<<batch, 512, 0, stream>>>(x, coef, out);
}